// Round 1
// baseline (1656.760 us; speedup 1.0000x reference)
//
#include <hip/hip_runtime.h>
#include <math.h>

#define B 8192
#define FA 848
#define FB 600
#define FC 264
#define ND 13
#define F 1725
#define N1 1024
#define N2 512
#define N3 256
#define NCROSS 4
#define EPS 1e-5f

// ---------------- gather + concat: h[r][j] ----------------
__global__ __launch_bounds__(256) void gather_kernel(
    const int* __restrict__ sparse, const float* __restrict__ dense,
    const float* __restrict__ ea, const float* __restrict__ eb,
    const float* __restrict__ ec, float* __restrict__ h) {
  int r = blockIdx.x;
  const int* sp = sparse + r * 26;
  float* hr = h + (size_t)r * F;
  for (int j = threadIdx.x; j < F; j += 256) {
    float v;
    if (j < FA) {
      int t = j / 106, c = j - t * 106;
      v = ea[(size_t)t * 10600000 + (size_t)sp[t] * 106 + c];
    } else if (j < FA + FB) {
      int jj = j - FA; int t = jj / 60, c = jj - t * 60;
      v = eb[(size_t)t * 600000 + (size_t)sp[8 + t] * 60 + c];
    } else if (j < FA + FB + FC) {
      int jj = j - FA - FB; int t = jj / 33, c = jj - t * 33;
      v = ec[(size_t)t * 33000 + (size_t)sp[18 + t] * 33 + c];
    } else {
      v = dense[r * ND + (j - (FA + FB + FC))];
    }
    hr[j] = v;
  }
}

// ---------------- column stats (sum, sumsq) via chunked atomics ----------------
__global__ __launch_bounds__(256) void colstat_kernel(
    const float* __restrict__ X, int C, float* __restrict__ sums) {
  int j = blockIdx.x * 256 + threadIdx.x;
  if (j >= C) return;
  int rows_per = B / gridDim.y;
  int r0 = blockIdx.y * rows_per;
  int r1 = r0 + rows_per;
  float s = 0.f, ss = 0.f;
  for (int r = r0; r < r1; ++r) {
    float x = X[(size_t)r * C + j];
    s += x; ss += x * x;
  }
  atomicAdd(&sums[j], s);
  atomicAdd(&sums[C + j], ss);
}

__global__ __launch_bounds__(256) void finstat_kernel(
    const float* __restrict__ sums, int C, float* __restrict__ mi) {
  int j = blockIdx.x * 256 + threadIdx.x;
  if (j >= C) return;
  float m = sums[j] * (1.0f / B);
  float v = sums[C + j] * (1.0f / B) - m * m;
  mi[j] = m;
  mi[C + j] = rsqrtf(v + EPS);
}

// ---------------- apply BN (optional relu), in place ----------------
__global__ __launch_bounds__(256) void bnapply_kernel(
    float* __restrict__ X, int C, const float* __restrict__ mi, int relu) {
  int r = blockIdx.x;
  float* xr = X + (size_t)r * C;
  for (int j = threadIdx.x; j < C; j += 256) {
    float x = (xr[j] - mi[j]) * mi[C + j];
    if (relu) x = fmaxf(x, 0.f);
    xr[j] = x;
  }
}

// ---------------- cross network, row-resident in registers ----------------
// Computes 4 cross layers then immediately dots the result row with
// Wout[0:F], writing one float per row (never materializes out_cross).
__global__ __launch_bounds__(256) void cross_kernel(
    const float* __restrict__ hn, const float* __restrict__ cw,
    const float* __restrict__ cb, const float* __restrict__ wout,
    float* __restrict__ partial) {
  int r = blockIdx.x;
  int tid = threadIdx.x;
  const float* x0p = hn + (size_t)r * F;
  float x0[7], xi[7];
#pragma unroll
  for (int e = 0; e < 7; ++e) {
    int j = tid + e * 256;
    x0[e] = (j < F) ? x0p[j] : 0.f;
    xi[e] = x0[e];
  }
  __shared__ float red[8];
  int lane = tid & 63, wid = tid >> 6;
  for (int i = 0; i < NCROSS; ++i) {
    float local = 0.f;
#pragma unroll
    for (int e = 0; e < 7; ++e) {
      int j = tid + e * 256;
      if (j < F) local += xi[e] * cw[i * F + j];
    }
    for (int off = 32; off > 0; off >>= 1) local += __shfl_down(local, off, 64);
    if (lane == 0) red[wid] = local;
    __syncthreads();
    if (tid == 0) red[4] = red[0] + red[1] + red[2] + red[3];
    __syncthreads();
    float s = red[4];
#pragma unroll
    for (int e = 0; e < 7; ++e) {
      int j = tid + e * 256;
      if (j < F) xi[e] = fmaf(x0[e], s, cb[i * F + j] + xi[e]);
    }
    __syncthreads();  // guard red[] reuse
  }
  // fused dot with Wout[0:F]
  float local = 0.f;
#pragma unroll
  for (int e = 0; e < 7; ++e) {
    int j = tid + e * 256;
    if (j < F) local += xi[e] * wout[j];
  }
  for (int off = 32; off > 0; off >>= 1) local += __shfl_down(local, off, 64);
  if (lane == 0) red[wid] = local;
  __syncthreads();
  if (tid == 0) partial[r] = red[0] + red[1] + red[2] + red[3];
}

// ---------------- fp32 tiled GEMM: C = A[M,K] @ W[K,N] + bias ----------------
#define BM 64
#define BN 64
#define BK 16
__global__ __launch_bounds__(256) void gemm_kernel(
    const float* __restrict__ A, const float* __restrict__ W,
    const float* __restrict__ bias, float* __restrict__ Cmat,
    int M, int N, int K) {
  __shared__ float As[BK][BM + 4];
  __shared__ float Ws[BK][BN];
  int tx = threadIdx.x, ty = threadIdx.y;
  int tid = ty * 16 + tx;
  int row0 = blockIdx.y * BM, col0 = blockIdx.x * BN;
  float acc[4][4] = {};
  int ka = tid & 15, ma = tid >> 4;  // A staging: k, m-base
  int nw = tid & 63, kw = tid >> 6;  // W staging: n, k-base
  for (int k0 = 0; k0 < K; k0 += BK) {
#pragma unroll
    for (int mo = 0; mo < BM; mo += 16) {
      int m = ma + mo;
      As[ka][m] = (k0 + ka < K) ? A[(size_t)(row0 + m) * K + k0 + ka] : 0.f;
    }
#pragma unroll
    for (int ko = 0; ko < BK; ko += 4) {
      int k = kw + ko;
      Ws[k][nw] = (k0 + k < K) ? W[(size_t)(k0 + k) * N + col0 + nw] : 0.f;
    }
    __syncthreads();
#pragma unroll
    for (int k = 0; k < BK; ++k) {
      float4 a = *(const float4*)&As[k][ty * 4];
      float4 w = *(const float4*)&Ws[k][tx * 4];
      float av[4] = {a.x, a.y, a.z, a.w};
      float wv[4] = {w.x, w.y, w.z, w.w};
#pragma unroll
      for (int i = 0; i < 4; ++i)
#pragma unroll
        for (int j = 0; j < 4; ++j) acc[i][j] = fmaf(av[i], wv[j], acc[i][j]);
    }
    __syncthreads();
  }
#pragma unroll
  for (int i = 0; i < 4; ++i) {
    int row = row0 + ty * 4 + i;
#pragma unroll
    for (int j = 0; j < 4; ++j) {
      int col = col0 + tx * 4 + j;
      Cmat[(size_t)row * N + col] = acc[i][j] + bias[col];
    }
  }
}

// ---------------- final: logits = cross_part + d3 . Wout[F:], sigmoid ----------------
__global__ __launch_bounds__(256) void final_kernel(
    const float* __restrict__ partial, const float* __restrict__ d3,
    const float* __restrict__ wout, float* __restrict__ out) {
  int r = blockIdx.x, tid = threadIdx.x;
  float local = d3[(size_t)r * N3 + tid] * wout[F + tid];
  for (int off = 32; off > 0; off >>= 1) local += __shfl_down(local, off, 64);
  __shared__ float red[4];
  int lane = tid & 63, wid = tid >> 6;
  if (lane == 0) red[wid] = local;
  __syncthreads();
  if (tid == 0) {
    float s = partial[r] + red[0] + red[1] + red[2] + red[3];
    out[r] = 1.0f / (1.0f + expf(-s));
  }
}

extern "C" void kernel_launch(void* const* d_in, const int* in_sizes, int n_in,
                              void* d_out, int out_size, void* d_ws,
                              size_t ws_size, hipStream_t stream) {
  const int* sparse = (const int*)d_in[0];
  const float* dense = (const float*)d_in[1];
  const float* ea = (const float*)d_in[2];
  const float* eb = (const float*)d_in[3];
  const float* ec = (const float*)d_in[4];
  const float* cw = (const float*)d_in[5];
  const float* cb = (const float*)d_in[6];
  const float* W1 = (const float*)d_in[7];
  const float* b1 = (const float*)d_in[8];
  const float* W2 = (const float*)d_in[9];
  const float* b2 = (const float*)d_in[10];
  const float* W3 = (const float*)d_in[11];
  const float* b3 = (const float*)d_in[12];
  const float* Wout = (const float*)d_in[13];
  float* out = (float*)d_out;

  float* ws = (float*)d_ws;
  size_t o = 0;
  float* hn = ws + o;      o += (size_t)B * F;    // 56.5 MB
  float* z1 = ws + o;      o += (size_t)B * N1;   // 33.5 MB
  float* z2 = ws + o;      o += (size_t)B * N2;   // 16.8 MB
  float* z3 = ws + o;      o += (size_t)B * N3;   //  8.4 MB
  float* cpart = ws + o;   o += B;                // 32 KB
  float* sums = ws + o;    o += 4096;
  float* mi = ws + o;      o += 4096;             // total ~115.4 MB

  dim3 blk2(16, 16);

  gather_kernel<<<B, 256, 0, stream>>>(sparse, dense, ea, eb, ec, hn);

  hipMemsetAsync(sums, 0, 4096 * sizeof(float), stream);
  colstat_kernel<<<dim3(7, 32), 256, 0, stream>>>(hn, F, sums);
  finstat_kernel<<<7, 256, 0, stream>>>(sums, F, mi);
  bnapply_kernel<<<B, 256, 0, stream>>>(hn, F, mi, 0);

  cross_kernel<<<B, 256, 0, stream>>>(hn, cw, cb, Wout, cpart);

  gemm_kernel<<<dim3(N1 / BN, B / BM), blk2, 0, stream>>>(hn, W1, b1, z1, B, N1, F);
  hipMemsetAsync(sums, 0, 4096 * sizeof(float), stream);
  colstat_kernel<<<dim3(4, 32), 256, 0, stream>>>(z1, N1, sums);
  finstat_kernel<<<4, 256, 0, stream>>>(sums, N1, mi);
  bnapply_kernel<<<B, 256, 0, stream>>>(z1, N1, mi, 1);

  gemm_kernel<<<dim3(N2 / BN, B / BM), blk2, 0, stream>>>(z1, W2, b2, z2, B, N2, N1);
  hipMemsetAsync(sums, 0, 4096 * sizeof(float), stream);
  colstat_kernel<<<dim3(2, 32), 256, 0, stream>>>(z2, N2, sums);
  finstat_kernel<<<2, 256, 0, stream>>>(sums, N2, mi);
  bnapply_kernel<<<B, 256, 0, stream>>>(z2, N2, mi, 1);

  gemm_kernel<<<dim3(N3 / BN, B / BM), blk2, 0, stream>>>(z2, W3, b3, z3, B, N3, N2);
  hipMemsetAsync(sums, 0, 4096 * sizeof(float), stream);
  colstat_kernel<<<dim3(1, 32), 256, 0, stream>>>(z3, N3, sums);
  finstat_kernel<<<1, 256, 0, stream>>>(sums, N3, mi);
  bnapply_kernel<<<B, 256, 0, stream>>>(z3, N3, mi, 1);

  final_kernel<<<B, 256, 0, stream>>>(cpart, z3, Wout, out);
}

// Round 2
// 889.096 us; speedup vs baseline: 1.8634x; 1.8634x over previous
//
#include <hip/hip_runtime.h>
#include <math.h>

#define B 8192
#define FA 848
#define FB 600
#define FC 264
#define ND 13
#define F 1725
#define KP1 1728   // F padded to multiple of 32
#define N1 1024
#define N2 512
#define N3 256
#define NCROSS 4
#define EPS 1e-5f

typedef __attribute__((ext_vector_type(4))) float f32x4;
typedef __attribute__((ext_vector_type(8))) short bf16x8;
typedef unsigned short u16;
typedef unsigned int u32;

__device__ __forceinline__ u16 f2bf(float x) {
  u32 b = __builtin_bit_cast(u32, x);
  u32 r = (b + 0x7fffu + ((b >> 16) & 1u)) >> 16;
  return (u16)r;
}

// ---------------- gather + concat: h[r][j] ----------------
__global__ __launch_bounds__(256) void gather_kernel(
    const int* __restrict__ sparse, const float* __restrict__ dense,
    const float* __restrict__ ea, const float* __restrict__ eb,
    const float* __restrict__ ec, float* __restrict__ h) {
  int r = blockIdx.x;
  const int* sp = sparse + r * 26;
  float* hr = h + (size_t)r * F;
  for (int j = threadIdx.x; j < F; j += 256) {
    float v;
    if (j < FA) {
      int t = j / 106, c = j - t * 106;
      v = ea[(size_t)t * 10600000 + (size_t)sp[t] * 106 + c];
    } else if (j < FA + FB) {
      int jj = j - FA; int t = jj / 60, c = jj - t * 60;
      v = eb[(size_t)t * 600000 + (size_t)sp[8 + t] * 60 + c];
    } else if (j < FA + FB + FC) {
      int jj = j - FA - FB; int t = jj / 33, c = jj - t * 33;
      v = ec[(size_t)t * 33000 + (size_t)sp[18 + t] * 33 + c];
    } else {
      v = dense[r * ND + (j - (FA + FB + FC))];
    }
    hr[j] = v;
  }
}

// ---------------- column stats (sum, sumsq) via chunked atomics ----------------
__global__ __launch_bounds__(256) void colstat_kernel(
    const float* __restrict__ X, int C, float* __restrict__ sums) {
  int j = blockIdx.x * 256 + threadIdx.x;
  if (j >= C) return;
  int rows_per = B / gridDim.y;
  int r0 = blockIdx.y * rows_per;
  int r1 = r0 + rows_per;
  float s = 0.f, ss = 0.f;
  for (int r = r0; r < r1; ++r) {
    float x = X[(size_t)r * C + j];
    s += x; ss += x * x;
  }
  atomicAdd(&sums[j], s);
  atomicAdd(&sums[C + j], ss);
}

__global__ __launch_bounds__(256) void finstat_kernel(
    const float* __restrict__ sums, int C, float* __restrict__ mi) {
  int j = blockIdx.x * 256 + threadIdx.x;
  if (j >= C) return;
  float m = sums[j] * (1.0f / B);
  float v = sums[C + j] * (1.0f / B) - m * m;
  mi[j] = m;
  mi[C + j] = rsqrtf(v + EPS);
}

// ---------------- BN for h: fp32 in place (for cross) + bf16 padded (for GEMM1) ----
__global__ __launch_bounds__(256) void bnapply_h_kernel(
    float* __restrict__ hn, const float* __restrict__ mi, u16* __restrict__ hbf) {
  int r = blockIdx.x;
  float* xr = hn + (size_t)r * F;
  u16* br = hbf + (size_t)r * KP1;
  for (int j = threadIdx.x; j < KP1; j += 256) {
    float x = 0.f;
    if (j < F) {
      x = (xr[j] - mi[j]) * mi[F + j];
      xr[j] = x;
    }
    br[j] = f2bf(x);
  }
}

// ---------------- BN + relu -> bf16 (for z1, z2) ----------------
__global__ __launch_bounds__(256) void bn_relu_bf_kernel(
    const float* __restrict__ X, int C, const float* __restrict__ mi,
    u16* __restrict__ out) {
  int r = blockIdx.x;
  const float* xr = X + (size_t)r * C;
  u16* br = out + (size_t)r * C;
  for (int j = threadIdx.x; j < C; j += 256) {
    float x = (xr[j] - mi[j]) * mi[C + j];
    x = fmaxf(x, 0.f);
    br[j] = f2bf(x);
  }
}

// ---------------- BN + relu, fp32 in place (for z3) ----------------
__global__ __launch_bounds__(256) void bn_relu_f32_kernel(
    float* __restrict__ X, int C, const float* __restrict__ mi) {
  int r = blockIdx.x;
  float* xr = X + (size_t)r * C;
  for (int j = threadIdx.x; j < C; j += 256) {
    float x = (xr[j] - mi[j]) * mi[C + j];
    xr[j] = fmaxf(x, 0.f);
  }
}

// ---------------- W[K][N] fp32 -> Wt[N][Kp] bf16 (transpose+cast, zero-pad K) ----
__global__ __launch_bounds__(256) void convw_kernel(
    const float* __restrict__ W, int K, int N, int Kp, u16* __restrict__ Wt) {
  __shared__ float t[32][33];
  int n0 = blockIdx.x * 32, k0 = blockIdx.y * 32;
  int tx = threadIdx.x, ty = threadIdx.y;  // 32 x 8
#pragma unroll
  for (int i = 0; i < 4; ++i) {
    int k = k0 + ty + i * 8;
    t[ty + i * 8][tx] = (k < K) ? W[(size_t)k * N + n0 + tx] : 0.f;
  }
  __syncthreads();
#pragma unroll
  for (int i = 0; i < 4; ++i) {
    int n = n0 + ty + i * 8;
    Wt[(size_t)n * Kp + k0 + tx] = f2bf(t[tx][ty + i * 8]);
  }
}

// ---------------- bf16 MFMA GEMM (m97 structure): C[M,N] = A[M,K] @ Bt[N,K]^T ----
// A, Bt bf16 row-major; K % 32 == 0; M % 128 == 0; N % 128 == 0.
__global__ __launch_bounds__(256) void gemm_bf16_kernel(
    const u16* __restrict__ A, const u16* __restrict__ Bt,
    float* __restrict__ C, int N, int K) {
  __shared__ u16 As[128 * 32];
  __shared__ u16 Bs[128 * 32];
  int tid = threadIdx.x;
  int lane = tid & 63;
  int wave = tid >> 6;
  int row0 = blockIdx.y * 128, col0 = blockIdx.x * 128;
  int wm = (wave >> 1) * 64, wn = (wave & 1) * 64;
  int mrow = lane & 15;  // m (or n) within a 16x16 tile
  int kq = lane >> 4;    // 0..3 : k-quarter

  f32x4 acc[4][4];
#pragma unroll
  for (int i = 0; i < 4; ++i)
#pragma unroll
    for (int j = 0; j < 4; ++j) acc[i][j] = (f32x4){0.f, 0.f, 0.f, 0.f};

  int kc = (tid & 3) * 8;  // staging: k-offset within tile
  const u16* Ag = A + (size_t)row0 * K;
  const u16* Bg = Bt + (size_t)col0 * K;

  for (int k0 = 0; k0 < K; k0 += 32) {
#pragma unroll
    for (int i = 0; i < 2; ++i) {
      int u = i * 256 + tid;
      int rr = u >> 2;  // row within tile
      __builtin_amdgcn_global_load_lds(
          (const __attribute__((address_space(1))) u32*)(Ag + (size_t)rr * K + k0 + kc),
          (__attribute__((address_space(3))) u32*)(As + u * 8), 16, 0, 0);
      __builtin_amdgcn_global_load_lds(
          (const __attribute__((address_space(1))) u32*)(Bg + (size_t)rr * K + k0 + kc),
          (__attribute__((address_space(3))) u32*)(Bs + u * 8), 16, 0, 0);
    }
    __syncthreads();
    bf16x8 af[4], bfr[4];
#pragma unroll
    for (int mi = 0; mi < 4; ++mi)
      af[mi] = *(const bf16x8*)(As + (wm + mi * 16 + mrow) * 32 + kq * 8);
#pragma unroll
    for (int ni = 0; ni < 4; ++ni)
      bfr[ni] = *(const bf16x8*)(Bs + (wn + ni * 16 + mrow) * 32 + kq * 8);
#pragma unroll
    for (int mi = 0; mi < 4; ++mi)
#pragma unroll
      for (int ni = 0; ni < 4; ++ni)
        acc[mi][ni] = __builtin_amdgcn_mfma_f32_16x16x32_bf16(
            af[mi], bfr[ni], acc[mi][ni], 0, 0, 0);
    __syncthreads();
  }
#pragma unroll
  for (int mi = 0; mi < 4; ++mi)
#pragma unroll
    for (int ni = 0; ni < 4; ++ni) {
      int col = col0 + wn + ni * 16 + mrow;
#pragma unroll
      for (int reg = 0; reg < 4; ++reg) {
        int row = row0 + wm + mi * 16 + kq * 4 + reg;
        C[(size_t)row * N + col] = acc[mi][ni][reg];
      }
    }
}

// ---------------- cross network, row-resident in registers ----------------
__global__ __launch_bounds__(256) void cross_kernel(
    const float* __restrict__ hn, const float* __restrict__ cw,
    const float* __restrict__ cb, const float* __restrict__ wout,
    float* __restrict__ partial) {
  int r = blockIdx.x;
  int tid = threadIdx.x;
  const float* x0p = hn + (size_t)r * F;
  float x0[7], xi[7];
#pragma unroll
  for (int e = 0; e < 7; ++e) {
    int j = tid + e * 256;
    x0[e] = (j < F) ? x0p[j] : 0.f;
    xi[e] = x0[e];
  }
  __shared__ float red[8];
  int lane = tid & 63, wid = tid >> 6;
  for (int i = 0; i < NCROSS; ++i) {
    float local = 0.f;
#pragma unroll
    for (int e = 0; e < 7; ++e) {
      int j = tid + e * 256;
      if (j < F) local += xi[e] * cw[i * F + j];
    }
    for (int off = 32; off > 0; off >>= 1) local += __shfl_down(local, off, 64);
    if (lane == 0) red[wid] = local;
    __syncthreads();
    if (tid == 0) red[4] = red[0] + red[1] + red[2] + red[3];
    __syncthreads();
    float s = red[4];
#pragma unroll
    for (int e = 0; e < 7; ++e) {
      int j = tid + e * 256;
      if (j < F) xi[e] = fmaf(x0[e], s, cb[i * F + j] + xi[e]);
    }
    __syncthreads();
  }
  float local = 0.f;
#pragma unroll
  for (int e = 0; e < 7; ++e) {
    int j = tid + e * 256;
    if (j < F) local += xi[e] * wout[j];
  }
  for (int off = 32; off > 0; off >>= 1) local += __shfl_down(local, off, 64);
  if (lane == 0) red[wid] = local;
  __syncthreads();
  if (tid == 0) partial[r] = red[0] + red[1] + red[2] + red[3];
}

// ---------------- final: logits = cross_part + d3 . Wout[F:], sigmoid ----------------
__global__ __launch_bounds__(256) void final_kernel(
    const float* __restrict__ partial, const float* __restrict__ d3,
    const float* __restrict__ wout, float* __restrict__ out) {
  int r = blockIdx.x, tid = threadIdx.x;
  float local = d3[(size_t)r * N3 + tid] * wout[F + tid];
  for (int off = 32; off > 0; off >>= 1) local += __shfl_down(local, off, 64);
  __shared__ float red[4];
  int lane = tid & 63, wid = tid >> 6;
  if (lane == 0) red[wid] = local;
  __syncthreads();
  if (tid == 0) {
    float s = partial[r] + red[0] + red[1] + red[2] + red[3];
    out[r] = 1.0f / (1.0f + expf(-s));
  }
}

extern "C" void kernel_launch(void* const* d_in, const int* in_sizes, int n_in,
                              void* d_out, int out_size, void* d_ws,
                              size_t ws_size, hipStream_t stream) {
  const int* sparse = (const int*)d_in[0];
  const float* dense = (const float*)d_in[1];
  const float* ea = (const float*)d_in[2];
  const float* eb = (const float*)d_in[3];
  const float* ec = (const float*)d_in[4];
  const float* cw = (const float*)d_in[5];
  const float* cb = (const float*)d_in[6];
  const float* W1 = (const float*)d_in[7];
  const float* W2 = (const float*)d_in[9];
  const float* W3 = (const float*)d_in[11];
  const float* Wout = (const float*)d_in[13];
  float* out = (float*)d_out;

  float* ws = (float*)d_ws;
  size_t o = 0;
  float* hn = ws + o;    o += (size_t)B * F;        // 56.5 MB (later reused for z2/z2bf)
  float* z1 = ws + o;    o += (size_t)B * N1;       // 33.5 MB (later reused for z3)
  float* cpart = ws + o; o += B;
  float* sums = ws + o;  o += 4096;
  float* mi = ws + o;    o += 4096;
  u16* hbf = (u16*)(ws + o);   o += (size_t)B * KP1 / 2;   // 28.3 MB
  u16* z1bf = (u16*)(ws + o);  o += (size_t)B * N1 / 2;    // 16.8 MB
  u16* W1t = (u16*)(ws + o);   o += (size_t)N1 * KP1 / 2;  // 3.5 MB
  u16* W2t = (u16*)(ws + o);   o += (size_t)N2 * N1 / 2;   // 1 MB
  u16* W3t = (u16*)(ws + o);   o += (size_t)N3 * N2 / 2;   // 0.25 MB
  // aliases (stream-ordered reuse):
  float* z2 = hn;                                   // after cross_kernel, hn is free
  u16* z2bf = (u16*)(hn + (size_t)B * N2);
  float* z3 = z1;                                   // after z1 -> z1bf, z1 is free

  // weight transpose+cast (independent of activations; do first)
  dim3 tb(32, 8);
  convw_kernel<<<dim3(N1 / 32, KP1 / 32), tb, 0, stream>>>(W1, F, N1, KP1, W1t);
  convw_kernel<<<dim3(N2 / 32, N1 / 32), tb, 0, stream>>>(W2, N1, N2, N1, W2t);
  convw_kernel<<<dim3(N3 / 32, N2 / 32), tb, 0, stream>>>(W3, N2, N3, N2, W3t);

  gather_kernel<<<B, 256, 0, stream>>>(sparse, dense, ea, eb, ec, hn);

  hipMemsetAsync(sums, 0, 4096 * sizeof(float), stream);
  colstat_kernel<<<dim3(7, 32), 256, 0, stream>>>(hn, F, sums);
  finstat_kernel<<<7, 256, 0, stream>>>(sums, F, mi);
  bnapply_h_kernel<<<B, 256, 0, stream>>>(hn, mi, hbf);

  cross_kernel<<<B, 256, 0, stream>>>(hn, cw, cb, Wout, cpart);

  gemm_bf16_kernel<<<dim3(N1 / 128, B / 128), 256, 0, stream>>>(hbf, W1t, z1, N1, KP1);
  hipMemsetAsync(sums, 0, 4096 * sizeof(float), stream);
  colstat_kernel<<<dim3(4, 32), 256, 0, stream>>>(z1, N1, sums);
  finstat_kernel<<<4, 256, 0, stream>>>(sums, N1, mi);
  bn_relu_bf_kernel<<<B, 256, 0, stream>>>(z1, N1, mi, z1bf);

  gemm_bf16_kernel<<<dim3(N2 / 128, B / 128), 256, 0, stream>>>(z1bf, W2t, z2, N2, N1);
  hipMemsetAsync(sums, 0, 4096 * sizeof(float), stream);
  colstat_kernel<<<dim3(2, 32), 256, 0, stream>>>(z2, N2, sums);
  finstat_kernel<<<2, 256, 0, stream>>>(sums, N2, mi);
  bn_relu_bf_kernel<<<B, 256, 0, stream>>>(z2, N2, mi, z2bf);

  gemm_bf16_kernel<<<dim3(N3 / 128, B / 128), 256, 0, stream>>>(z2bf, W3t, z3, N3, N2);
  hipMemsetAsync(sums, 0, 4096 * sizeof(float), stream);
  colstat_kernel<<<dim3(1, 32), 256, 0, stream>>>(z3, N3, sums);
  finstat_kernel<<<1, 256, 0, stream>>>(sums, N3, mi);
  bn_relu_f32_kernel<<<B, 256, 0, stream>>>(z3, N3, mi);

  final_kernel<<<B, 256, 0, stream>>>(cpart, z3, Wout, out);
}

// Round 3
// 649.134 us; speedup vs baseline: 2.5523x; 1.3697x over previous
//
#include <hip/hip_runtime.h>
#include <math.h>

#define B 8192
#define FA 848
#define FB 600
#define FC 264
#define ND 13
#define F 1725
#define KP1 1728   // F padded to multiple of 32
#define N1 1024
#define N2 512
#define N3 256
#define EPS 1e-5f

typedef __attribute__((ext_vector_type(4))) float f32x4;
typedef __attribute__((ext_vector_type(8))) short bf16x8;
typedef unsigned short u16;
typedef unsigned int u32;

__device__ __forceinline__ u16 f2bf(float x) {
  u32 b = __builtin_bit_cast(u32, x);
  u32 r = (b + 0x7fffu + ((b >> 16) & 1u)) >> 16;
  return (u16)r;
}
__device__ __forceinline__ float bf2f(u16 h) {
  return __builtin_bit_cast(float, (u32)h << 16);
}

// ---------------- gather + concat: h[r][j] (fp32) ----------------
__global__ __launch_bounds__(256) void gather_kernel(
    const int* __restrict__ sparse, const float* __restrict__ dense,
    const float* __restrict__ ea, const float* __restrict__ eb,
    const float* __restrict__ ec, float* __restrict__ h) {
  int r = blockIdx.x;
  const int* sp = sparse + r * 26;
  float* hr = h + (size_t)r * F;
  for (int j = threadIdx.x; j < F; j += 256) {
    float v;
    if (j < FA) {
      int t = j / 106, c = j - t * 106;
      v = ea[(size_t)t * 10600000 + (size_t)sp[t] * 106 + c];
    } else if (j < FA + FB) {
      int jj = j - FA; int t = jj / 60, c = jj - t * 60;
      v = eb[(size_t)t * 600000 + (size_t)sp[8 + t] * 60 + c];
    } else if (j < FA + FB + FC) {
      int jj = j - FA - FB; int t = jj / 33, c = jj - t * 33;
      v = ec[(size_t)t * 33000 + (size_t)sp[18 + t] * 33 + c];
    } else {
      v = dense[r * ND + (j - (FA + FB + FC))];
    }
    hr[j] = v;
  }
}

// ---------------- column stats for h (sum, sumsq) via chunked atomics ----------------
__global__ __launch_bounds__(256) void colstat_kernel(
    const float* __restrict__ X, int C, float* __restrict__ sums) {
  int j = blockIdx.x * 256 + threadIdx.x;
  if (j >= C) return;
  int rows_per = B / gridDim.y;
  int r0 = blockIdx.y * rows_per;
  int r1 = r0 + rows_per;
  float s = 0.f, ss = 0.f;
  for (int r = r0; r < r1; ++r) {
    float x = X[(size_t)r * C + j];
    s += x; ss += x * x;
  }
  atomicAdd(&sums[j], s);
  atomicAdd(&sums[C + j], ss);
}

__global__ __launch_bounds__(256) void finstat_kernel(
    const float* __restrict__ sums, int C, float* __restrict__ mi) {
  int j = blockIdx.x * 256 + threadIdx.x;
  if (j >= C) return;
  float m = sums[j] * (1.0f / B);
  float v = sums[C + j] * (1.0f / B) - m * m;
  mi[j] = m;
  mi[C + j] = rsqrtf(v + EPS);
}

// ---------------- h -> hbf (BN applied, bf16, K padded), packed u32 stores --------
__global__ __launch_bounds__(256) void bnapply_h_kernel(
    const float* __restrict__ h, const float* __restrict__ mi,
    u32* __restrict__ hbf) {
  int r = blockIdx.x;
  const float* xr = h + (size_t)r * F;
  u32* br = hbf + (size_t)r * (KP1 / 2);
  for (int jj = threadIdx.x; jj < KP1 / 2; jj += 256) {
    int c0 = jj * 2, c1 = c0 + 1;
    float x0 = 0.f, x1 = 0.f;
    if (c0 < F) x0 = (xr[c0] - mi[c0]) * mi[F + c0];
    if (c1 < F) x1 = (xr[c1] - mi[c1]) * mi[F + c1];
    br[jj] = (u32)f2bf(x0) | ((u32)f2bf(x1) << 16);
  }
}

// ---------------- prep: BN-folded cross/wout weights + recurrence constants -------
// cwf[i][j] = inv_j * w_i[j]  (w_0..3 = cross_w rows, w_4 = Wout[0:F])
// consts[0..4]  = off_i = sum_j m_j inv_j w_i[j]
// consts[5..8]  = d_0..d_3,  d_i = (sum_{j<i} cb_j) @ cw_i   (d_0 = 0)
// consts[9]     = e = (cb0+cb1+cb2+cb3) @ Wout[0:F]
__global__ __launch_bounds__(256) void prep_kernel(
    const float* __restrict__ mi, const float* __restrict__ cw,
    const float* __restrict__ cb, const float* __restrict__ wout,
    float* __restrict__ cwf, float* __restrict__ consts) {
  int tid = threadIdx.x;
  float acc9[9];
#pragma unroll
  for (int q = 0; q < 9; ++q) acc9[q] = 0.f;
  for (int j = tid; j < F; j += 256) {
    float m = mi[j], inv = mi[F + j];
    float w0 = cw[j], w1 = cw[F + j], w2 = cw[2 * F + j], w3 = cw[3 * F + j];
    float w4 = wout[j];
    cwf[j] = inv * w0;          acc9[0] += m * inv * w0;
    cwf[F + j] = inv * w1;      acc9[1] += m * inv * w1;
    cwf[2 * F + j] = inv * w2;  acc9[2] += m * inv * w2;
    cwf[3 * F + j] = inv * w3;  acc9[3] += m * inv * w3;
    cwf[4 * F + j] = inv * w4;  acc9[4] += m * inv * w4;
    float c1 = cb[j];
    float c2 = c1 + cb[F + j];
    float c3 = c2 + cb[2 * F + j];
    float c4 = c3 + cb[3 * F + j];
    acc9[5] += c1 * w1;
    acc9[6] += c2 * w2;
    acc9[7] += c3 * w3;
    acc9[8] += c4 * w4;
  }
  __shared__ float red[9][4];
  int lane = tid & 63, wid = tid >> 6;
#pragma unroll
  for (int q = 0; q < 9; ++q) {
    float v = acc9[q];
    for (int off = 32; off; off >>= 1) v += __shfl_down(v, off, 64);
    if (lane == 0) red[q][wid] = v;
  }
  __syncthreads();
  if (tid == 0) {
    float t[9];
#pragma unroll
    for (int q = 0; q < 9; ++q) t[q] = red[q][0] + red[q][1] + red[q][2] + red[q][3];
    consts[0] = t[0]; consts[1] = t[1]; consts[2] = t[2]; consts[3] = t[3];
    consts[4] = t[4];
    consts[5] = 0.f; consts[6] = t[5]; consts[7] = t[6]; consts[8] = t[7];
    consts[9] = t[8];
  }
}

// ---------------- GEMV: u[r,i] = h[r] @ cwf[i] - off_i, then scalar recurrence ----
__global__ __launch_bounds__(256) void gemv_cross_kernel(
    const float* __restrict__ h, const float* __restrict__ cwf,
    const float* __restrict__ consts, float* __restrict__ cpart) {
  int r = blockIdx.x, tid = threadIdx.x;
  const float* hr = h + (size_t)r * F;
  float p[5] = {0.f, 0.f, 0.f, 0.f, 0.f};
  for (int j = tid; j < F; j += 256) {
    float x = hr[j];
    p[0] += x * cwf[j];
    p[1] += x * cwf[F + j];
    p[2] += x * cwf[2 * F + j];
    p[3] += x * cwf[3 * F + j];
    p[4] += x * cwf[4 * F + j];
  }
  __shared__ float red[5][4];
  int lane = tid & 63, wid = tid >> 6;
#pragma unroll
  for (int i = 0; i < 5; ++i) {
    float v = p[i];
    for (int off = 32; off; off >>= 1) v += __shfl_down(v, off, 64);
    if (lane == 0) red[i][wid] = v;
  }
  __syncthreads();
  if (tid == 0) {
    float u[5];
#pragma unroll
    for (int i = 0; i < 5; ++i)
      u[i] = red[i][0] + red[i][1] + red[i][2] + red[i][3] - consts[i];
    float a = 1.f;
#pragma unroll
    for (int i = 0; i < 4; ++i) {
      float s = a * u[i] + consts[5 + i];
      a += s;
    }
    cpart[r] = a * u[4] + consts[9];
  }
}

// ---------------- W[K][N] fp32 -> Wt[N][Kp] bf16 (transpose+cast, zero-pad K) ----
__global__ __launch_bounds__(256) void convw_kernel(
    const float* __restrict__ W, int K, int N, int Kp, u16* __restrict__ Wt) {
  __shared__ float t[32][33];
  int n0 = blockIdx.x * 32, k0 = blockIdx.y * 32;
  int tx = threadIdx.x, ty = threadIdx.y;  // 32 x 8
#pragma unroll
  for (int i = 0; i < 4; ++i) {
    int k = k0 + ty + i * 8;
    t[ty + i * 8][tx] = (k < K) ? W[(size_t)k * N + n0 + tx] : 0.f;
  }
  __syncthreads();
#pragma unroll
  for (int i = 0; i < 4; ++i) {
    int n = n0 + ty + i * 8;
    Wt[(size_t)n * Kp + k0 + tx] = f2bf(t[tx][ty + i * 8]);
  }
}

// ---------------- bf16 MFMA GEMM + fused column-stats epilogue ----------------
// C[M,N] = A[M,K] @ Bt[N,K]^T.  Writes z (bf16 if OUT_BF else fp32) and
// atomically accumulates per-column sum/sumsq into gsum[0..N-1]/gsum[N..2N-1].
template <bool OUT_BF>
__global__ __launch_bounds__(256) void gemm_bf16_kernel(
    const u16* __restrict__ A, const u16* __restrict__ Bt,
    void* __restrict__ Cout, float* __restrict__ gsum, int N, int K) {
  __shared__ u16 As[128 * 32];
  __shared__ u16 Bs[128 * 32];
  int tid = threadIdx.x;
  int lane = tid & 63;
  int wave = tid >> 6;
  int row0 = blockIdx.y * 128, col0 = blockIdx.x * 128;
  int wm = (wave >> 1) * 64, wn = (wave & 1) * 64;
  int mrow = lane & 15;
  int kq = lane >> 4;

  f32x4 acc[4][4];
#pragma unroll
  for (int i = 0; i < 4; ++i)
#pragma unroll
    for (int j = 0; j < 4; ++j) acc[i][j] = (f32x4){0.f, 0.f, 0.f, 0.f};

  int kc = (tid & 3) * 8;
  const u16* Ag = A + (size_t)row0 * K;
  const u16* Bg = Bt + (size_t)col0 * K;

  for (int k0 = 0; k0 < K; k0 += 32) {
#pragma unroll
    for (int i = 0; i < 2; ++i) {
      int u = i * 256 + tid;
      int rr = u >> 2;
      __builtin_amdgcn_global_load_lds(
          (const __attribute__((address_space(1))) u32*)(Ag + (size_t)rr * K + k0 + kc),
          (__attribute__((address_space(3))) u32*)(As + u * 8), 16, 0, 0);
      __builtin_amdgcn_global_load_lds(
          (const __attribute__((address_space(1))) u32*)(Bg + (size_t)rr * K + k0 + kc),
          (__attribute__((address_space(3))) u32*)(Bs + u * 8), 16, 0, 0);
    }
    __syncthreads();
    bf16x8 af[4], bfr[4];
#pragma unroll
    for (int mi = 0; mi < 4; ++mi)
      af[mi] = *(const bf16x8*)(As + (wm + mi * 16 + mrow) * 32 + kq * 8);
#pragma unroll
    for (int ni = 0; ni < 4; ++ni)
      bfr[ni] = *(const bf16x8*)(Bs + (wn + ni * 16 + mrow) * 32 + kq * 8);
#pragma unroll
    for (int mi = 0; mi < 4; ++mi)
#pragma unroll
      for (int ni = 0; ni < 4; ++ni)
        acc[mi][ni] = __builtin_amdgcn_mfma_f32_16x16x32_bf16(
            af[mi], bfr[ni], acc[mi][ni], 0, 0, 0);
    __syncthreads();
  }

  // epilogue: store z (+ optional bf16 round) and column stats
  float* sred = (float*)As;  // 256 floats: [0..127]=sum, [128..255]=sumsq
  sred[tid] = 0.f;
  __syncthreads();
#pragma unroll
  for (int ni = 0; ni < 4; ++ni) {
    int col_l = wn + ni * 16 + mrow;
    int col = col0 + col_l;
    float s = 0.f, ss = 0.f;
#pragma unroll
    for (int mi = 0; mi < 4; ++mi) {
#pragma unroll
      for (int reg = 0; reg < 4; ++reg) {
        int row = row0 + wm + mi * 16 + kq * 4 + reg;
        float v = acc[mi][ni][reg];
        if (OUT_BF) {
          u16 hb = f2bf(v);
          v = bf2f(hb);
          ((u16*)Cout)[(size_t)row * N + col] = hb;
        } else {
          ((float*)Cout)[(size_t)row * N + col] = v;
        }
        s += v;
        ss += v * v;
      }
    }
    // reduce over kq (lanes xor 16, 32 share the same column)
    s += __shfl_xor(s, 16, 64);  s += __shfl_xor(s, 32, 64);
    ss += __shfl_xor(ss, 16, 64); ss += __shfl_xor(ss, 32, 64);
    if (kq == 0) {
      atomicAdd(&sred[col_l], s);
      atomicAdd(&sred[128 + col_l], ss);
    }
  }
  __syncthreads();
  if (tid < 128) {
    atomicAdd(&gsum[col0 + tid], sred[tid]);
    atomicAdd(&gsum[N + col0 + tid], sred[128 + tid]);
  }
}

// ---------------- BN + relu, bf16 -> bf16, 8 elems/thread ----------------
__global__ __launch_bounds__(256) void bn_relu_bb_kernel(
    const uint4* __restrict__ X, const float* __restrict__ mi,
    uint4* __restrict__ out, int Cmask, int total8) {
  int i = blockIdx.x * 256 + threadIdx.x;
  if (i >= total8) return;
  uint4 v = X[i];
  int colb = (i << 3) & Cmask;
  int C = Cmask + 1;
  u32 w[4] = {v.x, v.y, v.z, v.w};
  u32 o[4];
#pragma unroll
  for (int e = 0; e < 4; ++e) {
    int c0 = colb + e * 2, c1 = c0 + 1;
    float x0 = bf2f((u16)(w[e] & 0xffffu));
    float x1 = bf2f((u16)(w[e] >> 16));
    x0 = fmaxf((x0 - mi[c0]) * mi[C + c0], 0.f);
    x1 = fmaxf((x1 - mi[c1]) * mi[C + c1], 0.f);
    o[e] = (u32)f2bf(x0) | ((u32)f2bf(x1) << 16);
  }
  out[i] = make_uint4(o[0], o[1], o[2], o[3]);
}

// ---------------- BN + relu, fp32 in place (z3) ----------------
__global__ __launch_bounds__(256) void bn_relu_f32_kernel(
    float* __restrict__ X, int C, const float* __restrict__ mi) {
  int r = blockIdx.x;
  float* xr = X + (size_t)r * C;
  for (int j = threadIdx.x; j < C; j += 256) {
    float x = (xr[j] - mi[j]) * mi[C + j];
    xr[j] = fmaxf(x, 0.f);
  }
}

// ---------------- final: logits = cpart + d3 . Wout[F:], sigmoid ----------------
__global__ __launch_bounds__(256) void final_kernel(
    const float* __restrict__ cpart, const float* __restrict__ d3,
    const float* __restrict__ wout, float* __restrict__ out) {
  int r = blockIdx.x, tid = threadIdx.x;
  float local = d3[(size_t)r * N3 + tid] * wout[F + tid];
  for (int off = 32; off; off >>= 1) local += __shfl_down(local, off, 64);
  __shared__ float red[4];
  int lane = tid & 63, wid = tid >> 6;
  if (lane == 0) red[wid] = local;
  __syncthreads();
  if (tid == 0) {
    float s = cpart[r] + red[0] + red[1] + red[2] + red[3];
    out[r] = 1.0f / (1.0f + expf(-s));
  }
}

extern "C" void kernel_launch(void* const* d_in, const int* in_sizes, int n_in,
                              void* d_out, int out_size, void* d_ws,
                              size_t ws_size, hipStream_t stream) {
  const int* sparse = (const int*)d_in[0];
  const float* dense = (const float*)d_in[1];
  const float* ea = (const float*)d_in[2];
  const float* eb = (const float*)d_in[3];
  const float* ec = (const float*)d_in[4];
  const float* cw = (const float*)d_in[5];
  const float* cb = (const float*)d_in[6];
  const float* W1 = (const float*)d_in[7];
  const float* W2 = (const float*)d_in[9];
  const float* W3 = (const float*)d_in[11];
  const float* Wout = (const float*)d_in[13];
  float* out = (float*)d_out;

  float* ws = (float*)d_ws;
  size_t o = 0;
  float* h = ws + o;      o += (size_t)B * F;        // 56.5 MB fp32
  float* z3 = ws + o;     o += (size_t)B * N3;       //  8.4 MB fp32
  float* cpart = ws + o;  o += B;
  float* sums = ws + o;   o += 4096;
  float* mi = ws + o;     o += 4096;
  float* consts = ws + o; o += 16;
  float* cwf = ws + o;    o += 5 * F + 8;  o = (o + 7) & ~(size_t)7;
  u16* hbf = (u16*)(ws + o);  o += (size_t)B * KP1 / 2;
  u16* z1 = (u16*)(ws + o);   o += (size_t)B * N1 / 2;
  u16* z1n = (u16*)(ws + o);  o += (size_t)B * N1 / 2;
  u16* z2 = (u16*)(ws + o);   o += (size_t)B * N2 / 2;
  u16* z2n = (u16*)(ws + o);  o += (size_t)B * N2 / 2;
  u16* W1t = (u16*)(ws + o);  o += (size_t)N1 * KP1 / 2;
  u16* W2t = (u16*)(ws + o);  o += (size_t)N2 * N1 / 2;
  u16* W3t = (u16*)(ws + o);  o += (size_t)N3 * N2 / 2;

  dim3 tb(32, 8);
  convw_kernel<<<dim3(N1 / 32, KP1 / 32), tb, 0, stream>>>(W1, F, N1, KP1, W1t);
  convw_kernel<<<dim3(N2 / 32, N1 / 32), tb, 0, stream>>>(W2, N1, N2, N1, W2t);
  convw_kernel<<<dim3(N3 / 32, N2 / 32), tb, 0, stream>>>(W3, N2, N3, N2, W3t);

  gather_kernel<<<B, 256, 0, stream>>>(sparse, dense, ea, eb, ec, h);

  hipMemsetAsync(sums, 0, 4096 * sizeof(float), stream);
  colstat_kernel<<<dim3(7, 64), 256, 0, stream>>>(h, F, sums);
  finstat_kernel<<<7, 256, 0, stream>>>(sums, F, mi);

  bnapply_h_kernel<<<B, 256, 0, stream>>>(h, mi, (u32*)hbf);
  prep_kernel<<<1, 256, 0, stream>>>(mi, cw, cb, Wout, cwf, consts);
  gemv_cross_kernel<<<B, 256, 0, stream>>>(h, cwf, consts, cpart);

  hipMemsetAsync(sums, 0, 4096 * sizeof(float), stream);
  gemm_bf16_kernel<true><<<dim3(N1 / 128, B / 128), 256, 0, stream>>>(
      hbf, W1t, (void*)z1, sums, N1, KP1);
  finstat_kernel<<<4, 256, 0, stream>>>(sums, N1, mi);
  bn_relu_bb_kernel<<<(B * N1 / 8 + 255) / 256, 256, 0, stream>>>(
      (const uint4*)z1, mi, (uint4*)z1n, N1 - 1, B * N1 / 8);

  hipMemsetAsync(sums, 0, 4096 * sizeof(float), stream);
  gemm_bf16_kernel<true><<<dim3(N2 / 128, B / 128), 256, 0, stream>>>(
      z1n, W2t, (void*)z2, sums, N2, N1);
  finstat_kernel<<<2, 256, 0, stream>>>(sums, N2, mi);
  bn_relu_bb_kernel<<<(B * N2 / 8 + 255) / 256, 256, 0, stream>>>(
      (const uint4*)z2, mi, (uint4*)z2n, N2 - 1, B * N2 / 8);

  hipMemsetAsync(sums, 0, 4096 * sizeof(float), stream);
  gemm_bf16_kernel<false><<<dim3(N3 / 128, B / 128), 256, 0, stream>>>(
      z2n, W3t, (void*)z3, sums, N3, N2);
  finstat_kernel<<<1, 256, 0, stream>>>(sums, N3, mi);
  bn_relu_f32_kernel<<<B, 256, 0, stream>>>(z3, N3, mi);

  final_kernel<<<B, 256, 0, stream>>>(cpart, z3, Wout, out);
}